// Round 1
// baseline (1020.780 us; speedup 1.0000x reference)
//
#include <hip/hip_runtime.h>

// KMEANS encode+decode: B=65536, G=256, K=512, fp32 in/out.
// dist2[b,k] = x2[b] - 2*<x_b, mu_:,k> + m2[k]; argmin_k (ties -> first);
// recon[b,:] = mu[:, kmax[b]].
//
// Round 1: fp32-vector baseline, numerics replicate reference formula:
//   t = x2 - 2*dot  (2*dot exact, one rounding; fma contraction harmless since
//                    the product by 2.0 is exact)
//   d = t + m2[k]   (second rounding)
// Strict '<' scan in ascending k => ties pick first index, matching argmin.

constexpr int BATCH   = 65536;
constexpr int GDIM    = 256;
constexpr int KDIM    = 512;

constexpr int ROWS    = 64;            // batch rows per block
constexpr int THREADS = 256;           // 4 waves; thread = (row, k-chunk)
constexpr int KCHUNK  = KDIM / 4;      // 128 codes per thread
constexpr int XSTRIDE = GDIM + 1;      // 257: (r*257+g)%32 = (r+g)%32 -> <=2-way (free)

__global__ void transpose_kernel(const float* __restrict__ mu,
                                 float* __restrict__ muT) {
    // muT[k][g] = mu[g][k]; 512 blocks x 256 threads. Tiny (512 KB), L2-served.
    const int k = blockIdx.x;
    const int g = threadIdx.x;
    muT[k * GDIM + g] = mu[g * KDIM + k];
}

template <bool USE_MUT>
__global__ __launch_bounds__(THREADS)
void kmeans_kernel(const float* __restrict__ images,
                   const float* __restrict__ mu,
                   const float* __restrict__ muT,
                   float* __restrict__ out) {
    __shared__ float xs[ROWS * XSTRIDE];   // 64 x 257 fp32 = 65.8 KB
    __shared__ float m2s[KDIM];            // 2 KB
    __shared__ float bd_s[4][ROWS];
    __shared__ int   bk_s[4][ROWS];
    __shared__ int   kbest_s[ROWS];

    const int tid = threadIdx.x;
    const long long b0 = (long long)blockIdx.x * ROWS;

    // ---- Stage image tile into LDS (coalesced float4) ----
    {
        const float4* img4 = (const float4*)(images + b0 * GDIM);
        #pragma unroll
        for (int i = 0; i < ROWS * (GDIM / 4) / THREADS; ++i) {  // 16 iters
            const int idx = tid + i * THREADS;                   // 0..4095
            const int r = idx >> 6;                              // / 64
            const int c = idx & 63;
            const float4 v = img4[idx];
            float* dst = &xs[r * XSTRIDE + c * 4];
            dst[0] = v.x; dst[1] = v.y; dst[2] = v.z; dst[3] = v.w;
        }
    }

    // ---- m2[k] = sum_g mu[g,k]^2 (coalesced: lane -> k) ----
    {
        float s0 = 0.f, s1 = 0.f;
        for (int g = 0; g < GDIM; ++g) {
            const float a = mu[(size_t)g * KDIM + tid];
            const float b = mu[(size_t)g * KDIM + tid + 256];
            s0 += a * a;
            s1 += b * b;
        }
        m2s[tid]       = s0;
        m2s[tid + 256] = s1;
    }
    __syncthreads();

    const int r  = tid & (ROWS - 1);
    const int ch = tid >> 6;               // wave-uniform k-chunk id
    const float* xrow = &xs[r * XSTRIDE];

    // ---- x2 (per-thread, redundant across the 4 chunk threads; cheap) ----
    float x2 = 0.f;
    #pragma unroll 8
    for (int g = 0; g < GDIM; ++g) x2 += xrow[g] * xrow[g];

    // ---- dot products + running argmin over this thread's 128 codes ----
    float bestd = 3.402823466e+38f;
    int   bestk = 0;
    const int k0base = ch * KCHUNK;
    for (int kt = 0; kt < KCHUNK; kt += 8) {
        const int k0 = k0base + kt;
        float acc[8];
        #pragma unroll
        for (int j = 0; j < 8; ++j) acc[j] = 0.f;
        const float* mp = mu + k0;        // wave-uniform -> broadcast loads
        #pragma unroll 4
        for (int g = 0; g < GDIM; ++g) {
            const float xv = xrow[g];
            const float4 a = *(const float4*)(mp + (size_t)g * KDIM);
            const float4 b = *(const float4*)(mp + (size_t)g * KDIM + 4);
            acc[0] += xv * a.x;  acc[1] += xv * a.y;
            acc[2] += xv * a.z;  acc[3] += xv * a.w;
            acc[4] += xv * b.x;  acc[5] += xv * b.y;
            acc[6] += xv * b.z;  acc[7] += xv * b.w;
        }
        #pragma unroll
        for (int j = 0; j < 8; ++j) {
            const float t = x2 - 2.0f * acc[j];   // one rounding (x2 - 2*dot)
            const float d = t + m2s[k0 + j];      // second rounding
            if (d < bestd) { bestd = d; bestk = k0 + j; }
        }
    }
    bd_s[ch][r] = bestd;
    bk_s[ch][r] = bestk;
    __syncthreads();

    // ---- reduce the 4 chunks; ascending chunk order + strict '<' keeps
    //      the lowest k on ties ----
    if (tid < ROWS) {
        float bd = bd_s[0][tid];
        int   bk = bk_s[0][tid];
        #pragma unroll
        for (int c = 1; c < 4; ++c) {
            const float d = bd_s[c][tid];
            if (d < bd) { bd = d; bk = bk_s[c][tid]; }
        }
        kbest_s[tid] = bk;
    }
    __syncthreads();

    // ---- recon: copy codebook column (exact fp32 values) ----
    if (USE_MUT) {
        float4* out4 = (float4*)(out + b0 * GDIM);
        #pragma unroll
        for (int i = 0; i < ROWS * (GDIM / 4) / THREADS; ++i) {
            const int idx = tid + i * THREADS;
            const int rr = idx >> 6;
            const int cc = idx & 63;
            out4[idx] = *(const float4*)(muT + (size_t)kbest_s[rr] * GDIM + cc * 4);
        }
    } else {
        // Fallback without workspace: strided gather straight from mu (L2).
        for (int i = tid; i < ROWS * GDIM; i += THREADS) {
            const int rr = i >> 8;        // / GDIM
            const int gg = i & (GDIM - 1);
            out[b0 * GDIM + i] = mu[(size_t)gg * KDIM + kbest_s[rr]];
        }
    }
}

extern "C" void kernel_launch(void* const* d_in, const int* in_sizes, int n_in,
                              void* d_out, int out_size, void* d_ws, size_t ws_size,
                              hipStream_t stream) {
    const float* images = (const float*)d_in[0];   // (B, G) fp32
    const float* mu     = (const float*)d_in[1];   // (G, K) fp32
    float* out = (float*)d_out;                    // (B, G) fp32

    const size_t muT_bytes = (size_t)KDIM * GDIM * sizeof(float);  // 512 KB
    const bool use_mut = (ws_size >= muT_bytes) && (d_ws != nullptr);
    float* muT = (float*)d_ws;

    const int nblocks = BATCH / ROWS;  // 1024

    if (use_mut) {
        transpose_kernel<<<KDIM, GDIM, 0, stream>>>(mu, muT);
        kmeans_kernel<true><<<nblocks, THREADS, 0, stream>>>(images, mu, muT, out);
    } else {
        kmeans_kernel<false><<<nblocks, THREADS, 0, stream>>>(images, mu, nullptr, out);
    }
}